// Round 1
// baseline (22.884 us; speedup 1.0000x reference)
//
#include <hip/hip_runtime.h>
#include <math.h>

#define HIDDEN 2048
#define IN_F 350

__device__ __forceinline__ float sigmoidf_(float v) { return 1.0f / (1.0f + expf(-v)); }

// Computes the 350-element feature vector from x (133 keypoint pairs) into LDS.
// Executed redundantly by every block of the first kernel (reads only 1 KB).
__device__ void compute_feat(const float* __restrict__ x, float* feat) {
    __shared__ float sc[12];
    const int t = threadIdx.x;
    if (t == 0) {
        sc[0] = x[0];   sc[1] = x[1];     // src_body  = kp[0]
        sc[2] = x[106]; sc[3] = x[107];   // src_face  = kp[53]
        sc[4] = x[200]; sc[5] = x[201];   // src_left  = kp[100]
        sc[6] = x[242]; sc[7] = x[243];   // src_right = kp[121]
        float lminx = x[182], lmaxx = x[182], lminy = x[183], lmaxy = x[183];
        for (int j = 1; j < 21; ++j) {
            float vx = x[182 + 2*j], vy = x[183 + 2*j];
            lminx = fminf(lminx, vx); lmaxx = fmaxf(lmaxx, vx);
            lminy = fminf(lminy, vy); lmaxy = fmaxf(lmaxy, vy);
        }
        float wl = lmaxx - lminx, hl = lmaxy - lminy;
        float rminx = x[224], rmaxx = x[224], rminy = x[225], rmaxy = x[225];
        for (int j = 1; j < 21; ++j) {
            float vx = x[224 + 2*j], vy = x[225 + 2*j];
            rminx = fminf(rminx, vx); rmaxx = fmaxf(rmaxx, vx);
            rminy = fminf(rminy, vy); rmaxy = fmaxf(rmaxy, vy);
        }
        float wr = rmaxx - rminx, hr = rmaxy - rminy;
        bool okl = (wl != 0.0f) && (hl != 0.0f);
        bool okr = (wr != 0.0f) && (hr != 0.0f);
        sc[8]  = okl ? wl : 1.0f;  sc[9]  = okl ? hl : 1.0f;
        sc[10] = okr ? wr : 1.0f;  sc[11] = okr ? hr : 1.0f;
    }
    __syncthreads();
    const float sbx = sc[0], sby = sc[1], sfx = sc[2], sfy = sc[3];
    const float slx = sc[4], sly = sc[5], srx = sc[6], sry = sc[7];
    const float dlx = sc[8], dly = sc[9], drx = sc[10], dry = sc[11];
    for (int k = t; k < 133; k += blockDim.x) {
        float vx = x[2*k], vy = x[2*k + 1];
        if (k < 17) {                 // body @ 0
            feat[2*k]   = vx - sbx;  feat[2*k+1] = vy - sby;
        } else if (k < 23) {          // feet @ 34 (== 2*k)
            feat[2*k]   = vx;        feat[2*k+1] = vy;
        } else if (k < 91) {          // face @ 46 (== 2*k)
            feat[2*k]   = vx - sfx;  feat[2*k+1] = vy - sfy;
        } else if (k < 112) {         // left hand
            int j = k - 91;
            feat[182 + 2*j] = (vx - slx) / dlx;  feat[183 + 2*j] = (vy - sly) / dly;
            feat[266 + 2*j] = vx - sbx;          feat[267 + 2*j] = vy - sby;   // chin2l
        } else {                      // right hand
            int j = k - 112;
            feat[224 + 2*j] = (vx - srx) / drx;  feat[225 + 2*j] = (vy - sry) / dry;
            feat[308 + 2*j] = vx - sbx;          feat[309 + 2*j] = vy - sby;   // chin2r
        }
    }
    __syncthreads();
}

// Layer 0: h=c=0  =>  gate f is dead (sigmoid(f)*c == 0), W_hh unused.
// One block (3 waves = gates i,g,o) per hidden unit. K = 350.
__global__ __launch_bounds__(192) void lstm0_kernel(
    const float* __restrict__ x, const float* __restrict__ Wih,
    const float* __restrict__ bih, const float* __restrict__ bhh,
    float* __restrict__ h_out)
{
    __shared__ float feat[IN_F];
    __shared__ float gate_s[3];
    compute_feat(x, feat);
    const int j = blockIdx.x;
    const int wave = threadIdx.x >> 6;
    const int lane = threadIdx.x & 63;
    const int gate = (wave == 0) ? 0 : (wave == 1 ? 2 : 3);   // i, g, o
    const int row = gate * HIDDEN + j;
    const float* wr = Wih + (size_t)row * IN_F;
    float acc = 0.0f;
    for (int i = lane; i < IN_F; i += 64) acc += wr[i] * feat[i];
    #pragma unroll
    for (int off = 32; off; off >>= 1) acc += __shfl_down(acc, off);
    if (lane == 0) gate_s[wave] = acc + bih[row] + bhh[row];
    __syncthreads();
    if (threadIdx.x == 0) {
        float c = sigmoidf_(gate_s[0]) * tanhf(gate_s[1]);
        h_out[j] = sigmoidf_(gate_s[2]) * tanhf(c);
    }
}

// Layer 1: identical algebra (h=c=0 again), K = 2048, float4 loads.
__global__ __launch_bounds__(192) void lstm1_kernel(
    const float* __restrict__ h_in, const float* __restrict__ Wih,
    const float* __restrict__ bih, const float* __restrict__ bhh,
    float* __restrict__ h_out)
{
    __shared__ float gate_s[3];
    const int j = blockIdx.x;
    const int wave = threadIdx.x >> 6;
    const int lane = threadIdx.x & 63;
    const int gate = (wave == 0) ? 0 : (wave == 1 ? 2 : 3);   // i, g, o
    const int row = gate * HIDDEN + j;
    const float4* wr4 = (const float4*)(Wih + (size_t)row * HIDDEN);
    const float4* h4  = (const float4*)h_in;
    float acc = 0.0f;
    #pragma unroll
    for (int i = lane; i < HIDDEN / 4; i += 64) {
        float4 w = wr4[i]; float4 v = h4[i];
        acc += w.x * v.x + w.y * v.y + w.z * v.z + w.w * v.w;
    }
    #pragma unroll
    for (int off = 32; off; off >>= 1) acc += __shfl_down(acc, off);
    if (lane == 0) gate_s[wave] = acc + bih[row] + bhh[row];
    __syncthreads();
    if (threadIdx.x == 0) {
        float c = sigmoidf_(gate_s[0]) * tanhf(gate_s[1]);
        h_out[j] = sigmoidf_(gate_s[2]) * tanhf(c);
    }
}

// out[r] = fc_w[r,:] . h2 + fc_b[r], r in [0,350). One wave per row.
__global__ __launch_bounds__(256) void fc_kernel(
    const float* __restrict__ h_in, const float* __restrict__ W,
    const float* __restrict__ b, float* __restrict__ out)
{
    const int wave = threadIdx.x >> 6;
    const int lane = threadIdx.x & 63;
    const int r = blockIdx.x * 4 + wave;
    if (r >= IN_F) return;
    const float4* wr4 = (const float4*)(W + (size_t)r * HIDDEN);
    const float4* h4  = (const float4*)h_in;
    float acc = 0.0f;
    #pragma unroll
    for (int i = lane; i < HIDDEN / 4; i += 64) {
        float4 w = wr4[i]; float4 v = h4[i];
        acc += w.x * v.x + w.y * v.y + w.z * v.z + w.w * v.w;
    }
    #pragma unroll
    for (int off = 32; off; off >>= 1) acc += __shfl_down(acc, off);
    if (lane == 0) out[r] = acc + b[r];
}

extern "C" void kernel_launch(void* const* d_in, const int* in_sizes, int n_in,
                              void* d_out, int out_size, void* d_ws, size_t ws_size,
                              hipStream_t stream) {
    const float* x     = (const float*)d_in[0];
    const float* W_ih0 = (const float*)d_in[1];
    // d_in[2] = W_hh0 : unused (h0 == 0)
    const float* b_ih0 = (const float*)d_in[3];
    const float* b_hh0 = (const float*)d_in[4];
    const float* W_ih1 = (const float*)d_in[5];
    // d_in[6] = W_hh1 : unused (h == 0 for cell 2 as well)
    const float* b_ih1 = (const float*)d_in[7];
    const float* b_hh1 = (const float*)d_in[8];
    const float* fc_w  = (const float*)d_in[9];
    const float* fc_b  = (const float*)d_in[10];

    float* ws = (float*)d_ws;
    float* h1 = ws;            // 2048 floats
    float* h2 = ws + HIDDEN;   // 2048 floats

    lstm0_kernel<<<HIDDEN, 192, 0, stream>>>(x, W_ih0, b_ih0, b_hh0, h1);
    lstm1_kernel<<<HIDDEN, 192, 0, stream>>>(h1, W_ih1, b_ih1, b_hh1, h2);
    fc_kernel<<<(IN_F + 3) / 4, 256, 0, stream>>>(h2, fc_w, fc_b, (float*)d_out);
}